// Round 6
// baseline (325.506 us; speedup 1.0000x reference)
//
#include <hip/hip_runtime.h>
#include <math.h>

#define HDIM 256
#define KDIM 16
#define SDIM 200
#define BDIM 512
#define NROWS (BDIM * SDIM)   // 102400

typedef __bf16 bf16x8 __attribute__((ext_vector_type(8)));
typedef float  f32x4  __attribute__((ext_vector_type(4)));

#define MFMA(a, b, c) __builtin_amdgcn_mfma_f32_16x16x32_bf16(a, b, c, 0, 0, 0)

// ---------------------------------------------------------------------------
// Pack all weights TRANSPOSED into fragment-ready split-bf16 chunks.
// Chunk layout (per matrix): for kc (K-chunks of 32) x dt (16-wide d-tiles):
//   hi[(kc*DT + dt)*512 + l*8 + j] = bf16_hi( Wt[dt*16 + (l&15)][kc*32 + (l>>4)*8 + j] )
// where Wt[d][k] = src[k*N + d] for k<256, = bias[d] at k==256 (bias chunk), 0 else.
// A lane's A-frag is then ONE coalesced b128 load.
// W1/W2: 9 kc (incl. bias) x 16 dt = 73728 elems. W3: 8 kc x 1 dt = 4096.
// ---------------------------------------------------------------------------
__global__ __launch_bounds__(256) void pack_all(
    const float* __restrict__ W1, const float* __restrict__ b1,
    const float* __restrict__ W2, const float* __restrict__ b2,
    const float* __restrict__ W3,
    __bf16* __restrict__ w1h, __bf16* __restrict__ w1l,
    __bf16* __restrict__ w2h, __bf16* __restrict__ w2l,
    __bf16* __restrict__ w3h, __bf16* __restrict__ w3l)
{
    int gid = blockIdx.x * 256 + threadIdx.x;
    const float *src, *bias;
    __bf16 *oh, *ol;
    int e, N;
    if (gid < 73728)       { src = W1; bias = b1;      oh = w1h; ol = w1l; e = gid;          N = 256; }
    else if (gid < 147456) { src = W2; bias = b2;      oh = w2h; ol = w2l; e = gid - 73728;  N = 256; }
    else if (gid < 151552) { src = W3; bias = nullptr; oh = w3h; ol = w3l; e = gid - 147456; N = 16;  }
    else return;

    int j = e & 7, l = (e >> 3) & 63, c = e >> 9;
    int dt, kc;
    if (N == 256) { dt = c & 15; kc = c >> 4; } else { dt = 0; kc = c; }
    int d = dt * 16 + (l & 15);
    int k = kc * 32 + ((l >> 4) * 8) + j;
    float v = (k < 256) ? src[k * N + d] : ((k == 256 && bias) ? bias[d] : 0.f);
    __bf16 h = (__bf16)v;
    oh[e] = h;
    ol[e] = (__bf16)(v - (float)h);
}

// ---------------------------------------------------------------------------
// Fused MLP + logits + softmax-K: one wave (64 thr) per 32 rows. ZERO LDS,
// ZERO barriers. All GEMMs computed transposed (C^T = W^T · X^T) so each
// X-row stays in lane col=l&15 throughout; layer outputs become next-layer
// B-frags via an in-register __shfl dance (no LDS round-trip).
// Split-bf16 3-pass everywhere; bias folded as a K-extension one-hot chunk.
// ---------------------------------------------------------------------------
__global__ __launch_bounds__(64, 2) void mlp_fused(
    const float* __restrict__ X, const int* __restrict__ mask,
    const __bf16* __restrict__ w1h, const __bf16* __restrict__ w1l,
    const __bf16* __restrict__ w2h, const __bf16* __restrict__ w2l,
    const __bf16* __restrict__ w3h, const __bf16* __restrict__ w3l,
    float* __restrict__ P)
{
    const int l = threadIdx.x;
    const int q = l >> 4, m = l & 15;
    const long R = (long)blockIdx.x * 32;

    f32x4 acc1[16][2];   // [d1-tile][row-tile] : C^T of layer 1 (128 VGPRs)
    #pragma unroll
    for (int t = 0; t < 16; ++t) {
        acc1[t][0] = (f32x4){0.f, 0.f, 0.f, 0.f};
        acc1[t][1] = (f32x4){0.f, 0.f, 0.f, 0.f};
    }

    // ---- GEMM1: acc1 = W1^T · X^T  (K = 256 in 8 chunks of 32) ----
    #pragma unroll 1
    for (int kc = 0; kc < 8; ++kc) {
        bf16x8 bxh[2], bxl[2];
        #pragma unroll
        for (int rt = 0; rt < 2; ++rt) {
            const float* xp = X + (R + rt * 16 + m) * HDIM + kc * 32 + q * 8;
            float4 f0 = *(const float4*)xp;
            float4 f1 = *(const float4*)(xp + 4);
            float xv[8] = {f0.x, f0.y, f0.z, f0.w, f1.x, f1.y, f1.z, f1.w};
            #pragma unroll
            for (int j2 = 0; j2 < 8; ++j2) {
                __bf16 h = (__bf16)xv[j2];
                bxh[rt][j2] = h;
                bxl[rt][j2] = (__bf16)(xv[j2] - (float)h);
            }
        }
        #pragma unroll
        for (int dt = 0; dt < 16; ++dt) {
            bf16x8 ah = *(const bf16x8*)(w1h + (kc * 16 + dt) * 512 + l * 8);
            bf16x8 al = *(const bf16x8*)(w1l + (kc * 16 + dt) * 512 + l * 8);
            #pragma unroll
            for (int rt = 0; rt < 2; ++rt) {
                acc1[dt][rt] = MFMA(ah, bxh[rt], acc1[dt][rt]);
                acc1[dt][rt] = MFMA(al, bxh[rt], acc1[dt][rt]);
                acc1[dt][rt] = MFMA(ah, bxl[rt], acc1[dt][rt]);
            }
        }
    }
    {   // bias chunk (k=256 one-hot: q==0, j==0)
        bf16x8 bx1;
        #pragma unroll
        for (int j2 = 0; j2 < 8; ++j2) bx1[j2] = (__bf16)0.f;
        bx1[0] = (q == 0) ? (__bf16)1.f : (__bf16)0.f;
        #pragma unroll
        for (int dt = 0; dt < 16; ++dt) {
            bf16x8 ah = *(const bf16x8*)(w1h + (128 + dt) * 512 + l * 8);
            bf16x8 al = *(const bf16x8*)(w1l + (128 + dt) * 512 + l * 8);
            #pragma unroll
            for (int rt = 0; rt < 2; ++rt) {
                acc1[dt][rt] = MFMA(ah, bx1, acc1[dt][rt]);
                acc1[dt][rt] = MFMA(al, bx1, acc1[dt][rt]);
            }
        }
    }

    // ---- ReLU + in-register reshuffle: acc1 -> GEMM2 B-frags ----
    // B-frag[kc2] lane (q,m) needs k=d1 in [32*kc2+8q, +8): tile 2*kc2+(q>>1),
    // j<4 from provider quad 2*(q&1) reg j, j>=4 from quad 2*(q&1)+1 reg j-4.
    bf16x8 f2h[8][2], f2l[8][2];
    #pragma unroll
    for (int kc2 = 0; kc2 < 8; ++kc2) {
        #pragma unroll
        for (int rt = 0; rt < 2; ++rt) {
            float g[8];
            #pragma unroll
            for (int i = 0; i < 4; ++i) {
                float s0 = fmaxf(acc1[2 * kc2 + 0][rt][i], 0.f);
                float s1 = fmaxf(acc1[2 * kc2 + 1][rt][i], 0.f);
                int lane_lo = ((2 * (q & 1)) << 4) | m;
                float glo0 = __shfl(s0, lane_lo);
                float ghi0 = __shfl(s0, lane_lo + 16);
                float glo1 = __shfl(s1, lane_lo);
                float ghi1 = __shfl(s1, lane_lo + 16);
                g[i]     = (q < 2) ? glo0 : glo1;
                g[4 + i] = (q < 2) ? ghi0 : ghi1;
            }
            #pragma unroll
            for (int j2 = 0; j2 < 8; ++j2) {
                __bf16 h = (__bf16)g[j2];
                f2h[kc2][rt][j2] = h;
                f2l[kc2][rt][j2] = (__bf16)(g[j2] - (float)h);
            }
        }
    }

    // ---- GEMM2 (d2 in quarters) + on-the-fly GEMM3 (logits) ----
    f32x4 acc3[2] = {(f32x4){0.f, 0.f, 0.f, 0.f}, (f32x4){0.f, 0.f, 0.f, 0.f}};
    #pragma unroll 1
    for (int qd = 0; qd < 4; ++qd) {
        f32x4 acc2[4][2];
        #pragma unroll
        for (int t = 0; t < 4; ++t) {
            acc2[t][0] = (f32x4){0.f, 0.f, 0.f, 0.f};
            acc2[t][1] = (f32x4){0.f, 0.f, 0.f, 0.f};
        }
        #pragma unroll
        for (int kc2 = 0; kc2 < 8; ++kc2) {
            #pragma unroll
            for (int dtl = 0; dtl < 4; ++dtl) {
                int c = kc2 * 16 + qd * 4 + dtl;
                bf16x8 ah = *(const bf16x8*)(w2h + c * 512 + l * 8);
                bf16x8 al = *(const bf16x8*)(w2l + c * 512 + l * 8);
                #pragma unroll
                for (int rt = 0; rt < 2; ++rt) {
                    acc2[dtl][rt] = MFMA(ah, f2h[kc2][rt], acc2[dtl][rt]);
                    acc2[dtl][rt] = MFMA(al, f2h[kc2][rt], acc2[dtl][rt]);
                    acc2[dtl][rt] = MFMA(ah, f2l[kc2][rt], acc2[dtl][rt]);
                }
            }
        }
        {   // bias chunk for layer 2
            bf16x8 bx1;
            #pragma unroll
            for (int j2 = 0; j2 < 8; ++j2) bx1[j2] = (__bf16)0.f;
            bx1[0] = (q == 0) ? (__bf16)1.f : (__bf16)0.f;
            #pragma unroll
            for (int dtl = 0; dtl < 4; ++dtl) {
                int c = 128 + qd * 4 + dtl;
                bf16x8 ah = *(const bf16x8*)(w2h + c * 512 + l * 8);
                bf16x8 al = *(const bf16x8*)(w2l + c * 512 + l * 8);
                #pragma unroll
                for (int rt = 0; rt < 2; ++rt) {
                    acc2[dtl][rt] = MFMA(ah, bx1, acc2[dtl][rt]);
                    acc2[dtl][rt] = MFMA(al, bx1, acc2[dtl][rt]);
                }
            }
        }
        // ReLU + reshuffle quarter -> GEMM3 B-frags; accumulate logits.
        #pragma unroll
        for (int c = 0; c < 2; ++c) {
            bf16x8 f3h[2], f3l[2];
            #pragma unroll
            for (int rt = 0; rt < 2; ++rt) {
                float g[8];
                #pragma unroll
                for (int i = 0; i < 4; ++i) {
                    float s0 = fmaxf(acc2[2 * c + 0][rt][i], 0.f);
                    float s1 = fmaxf(acc2[2 * c + 1][rt][i], 0.f);
                    int lane_lo = ((2 * (q & 1)) << 4) | m;
                    float glo0 = __shfl(s0, lane_lo);
                    float ghi0 = __shfl(s0, lane_lo + 16);
                    float glo1 = __shfl(s1, lane_lo);
                    float ghi1 = __shfl(s1, lane_lo + 16);
                    g[i]     = (q < 2) ? glo0 : glo1;
                    g[4 + i] = (q < 2) ? ghi0 : ghi1;
                }
                #pragma unroll
                for (int j2 = 0; j2 < 8; ++j2) {
                    __bf16 h = (__bf16)g[j2];
                    f3h[rt][j2] = h;
                    f3l[rt][j2] = (__bf16)(g[j2] - (float)h);
                }
            }
            bf16x8 a3h = *(const bf16x8*)(w3h + (2 * qd + c) * 512 + l * 8);
            bf16x8 a3l = *(const bf16x8*)(w3l + (2 * qd + c) * 512 + l * 8);
            #pragma unroll
            for (int rt = 0; rt < 2; ++rt) {
                acc3[rt] = MFMA(a3h, f3h[rt], acc3[rt]);
                acc3[rt] = MFMA(a3l, f3h[rt], acc3[rt]);
                acc3[rt] = MFMA(a3h, f3l[rt], acc3[rt]);
            }
        }
    }

    // ---- softmax over k (d3 = 4q + r spread across quads, col m = row) ----
    #pragma unroll
    for (int rt = 0; rt < 2; ++rt) {
        float mx = fmaxf(fmaxf(acc3[rt][0], acc3[rt][1]),
                         fmaxf(acc3[rt][2], acc3[rt][3]));
        mx = fmaxf(mx, __shfl_xor(mx, 16));
        mx = fmaxf(mx, __shfl_xor(mx, 32));
        float e[4], s = 0.f;
        #pragma unroll
        for (int r = 0; r < 4; ++r) { e[r] = __expf(acc3[rt][r] - mx); s += e[r]; }
        s += __shfl_xor(s, 16);
        s += __shfl_xor(s, 32);
        long grow = R + rt * 16 + m;
        int mv = mask[grow];
        float inv = 0.25f / s;
        float4 o;
        if (mv) { o.x = e[0] * inv; o.y = e[1] * inv; o.z = e[2] * inv; o.w = e[3] * inv; }
        else    { o.x = o.y = o.z = o.w = -2500.0f; }   // (-10000)/sqrt(16)
        *(float4*)(P + grow * KDIM + 4 * q) = o;
    }
}

// ---------------------------------------------------------------------------
// Kernel 2 (unchanged from R5): per-b softmax over S (exp(-2500)==0 handles
// the mask) * time_f_w, then out[b,k,h] = sum_s X[b,s,h] * D[s,k].
// ---------------------------------------------------------------------------
__global__ __launch_bounds__(256) void softs_agg_kernel(
    const float* __restrict__ X, const float* __restrict__ tf,
    const float* __restrict__ P, float* __restrict__ out)
{
    __shared__ float wl[SDIM * KDIM];
    __shared__ float tfl[SDIM];
    __shared__ float psum[256];
    __shared__ float invk[KDIM];
    __shared__ float red[KDIM * HDIM];

    const int tid = threadIdx.x;
    const int b   = blockIdx.x;

    const float* Pb = P + (long)b * SDIM * KDIM;
    float ps = 0.f;
    #pragma unroll
    for (int t = 0; t < 13; ++t) {
        int i = tid + t * 256;
        if (i < SDIM * KDIM) {
            float e = __expf(Pb[i]);
            wl[i] = e;
            ps += e;
        }
    }
    psum[tid] = ps;
    if (tid < SDIM) tfl[tid] = tf[b * SDIM + tid];
    __syncthreads();

    if (tid < KDIM) {
        float s = 0.f;
        #pragma unroll
        for (int g = 0; g < 16; ++g) s += psum[tid + g * 16];
        invk[tid] = 1.f / s;
    }
    __syncthreads();

    #pragma unroll
    for (int t = 0; t < 13; ++t) {
        int i = tid + t * 256;
        if (i < SDIM * KDIM) wl[i] *= tfl[i >> 4] * invk[i & 15];
    }
    __syncthreads();

    const int wv = tid >> 6;
    const int sh = wv >> 1;
    const int hh = wv & 1;
    const int ln = tid & 63;

    float accx[KDIM], accy[KDIM];
    #pragma unroll
    for (int k = 0; k < KDIM; ++k) { accx[k] = 0.f; accy[k] = 0.f; }

    const float2* Xb  = (const float2*)(X + (long)b * SDIM * HDIM) + hh * 64 + ln;
    const f32x4*  wl4 = (const f32x4*)wl;
    const int s0 = sh * 100;
    #pragma unroll 4
    for (int si = 0; si < 100; ++si) {
        int s = s0 + si;
        float2 x = Xb[(long)s * (HDIM / 2)];
        f32x4 d0 = wl4[s * 4 + 0];
        f32x4 d1 = wl4[s * 4 + 1];
        f32x4 d2 = wl4[s * 4 + 2];
        f32x4 d3 = wl4[s * 4 + 3];
        #pragma unroll
        for (int j = 0; j < 4; ++j) {
            accx[0 + j]  = fmaf(x.x, d0[j], accx[0 + j]);
            accx[4 + j]  = fmaf(x.x, d1[j], accx[4 + j]);
            accx[8 + j]  = fmaf(x.x, d2[j], accx[8 + j]);
            accx[12 + j] = fmaf(x.x, d3[j], accx[12 + j]);
            accy[0 + j]  = fmaf(x.y, d0[j], accy[0 + j]);
            accy[4 + j]  = fmaf(x.y, d1[j], accy[4 + j]);
            accy[8 + j]  = fmaf(x.y, d2[j], accy[8 + j]);
            accy[12 + j] = fmaf(x.y, d3[j], accy[12 + j]);
        }
    }

    if (sh == 1) {
        #pragma unroll
        for (int k = 0; k < KDIM; ++k) {
            red[k * HDIM + hh * 128 + 2 * ln + 0] = accx[k];
            red[k * HDIM + hh * 128 + 2 * ln + 1] = accy[k];
        }
    }
    __syncthreads();
    if (sh == 0) {
        float* ob = out + (long)b * KDIM * HDIM + hh * 128 + 2 * ln;
        #pragma unroll
        for (int k = 0; k < KDIM; ++k) {
            float2 o;
            o.x = accx[k] + red[k * HDIM + hh * 128 + 2 * ln + 0];
            o.y = accy[k] + red[k * HDIM + hh * 128 + 2 * ln + 1];
            *(float2*)(ob + (long)k * HDIM) = o;
        }
    }
}

extern "C" void kernel_launch(void* const* d_in, const int* in_sizes, int n_in,
                              void* d_out, int out_size, void* d_ws, size_t ws_size,
                              hipStream_t stream) {
    (void)in_sizes; (void)n_in; (void)out_size; (void)ws_size;
    const float* X    = (const float*)d_in[0];
    const int*   mask = (const int*)  d_in[1];
    const float* tf   = (const float*)d_in[2];
    const float* W1   = (const float*)d_in[3];
    const float* b1   = (const float*)d_in[4];
    const float* W2   = (const float*)d_in[5];
    const float* b2   = (const float*)d_in[6];
    const float* W3   = (const float*)d_in[7];
    float* out = (float*)d_out;

    char* ws = (char*)d_ws;
    float*  P   = (float*)ws;                    // 102400*16*4 = 6,553,600 B
    __bf16* w1h = (__bf16*)(ws + 6553600);       // 73728 elems (147456 B) each:
    __bf16* w1l = w1h + 73728;
    __bf16* w2h = w1l + 73728;
    __bf16* w2l = w2h + 73728;
    __bf16* w3h = w2l + 73728;                   // 4096 elems each
    __bf16* w3l = w3h + 4096;

    pack_all<<<592, 256, 0, stream>>>(W1, b1, W2, b2, W3, w1h, w1l, w2h, w2l, w3h, w3l);
    mlp_fused<<<NROWS / 32, 64, 0, stream>>>(X, mask, w1h, w1l, w2h, w2l, w3h, w3l, P);
    softs_agg_kernel<<<BDIM, 256, 0, stream>>>(X, tf, P, out);
}

// Round 7
// 263.587 us; speedup vs baseline: 1.2349x; 1.2349x over previous
//
#include <hip/hip_runtime.h>
#include <math.h>

#define HDIM 256
#define KDIM 16
#define SDIM 200
#define BDIM 512
#define NROWS (BDIM * SDIM)   // 102400
#define TM 32                 // rows per block in kernel 1 (32KB LDS)

typedef __bf16 bf16x8 __attribute__((ext_vector_type(8)));
typedef __bf16 bf16x4 __attribute__((ext_vector_type(4)));
typedef float  f32x4  __attribute__((ext_vector_type(4)));

// ---------------------------------------------------------------------------
// Fused pack: W1, W2, W3 -> fragment-ready split-bf16 layout
//   dst[((k>>3)*N + n)*8 + (k&7)] = hi/lo bf16 of W[k*N + n]
// ---------------------------------------------------------------------------
__global__ __launch_bounds__(256) void pack_all(
    const float* __restrict__ W1, const float* __restrict__ W2,
    const float* __restrict__ W3,
    __bf16* __restrict__ w1h, __bf16* __restrict__ w1l,
    __bf16* __restrict__ w2h, __bf16* __restrict__ w2l,
    __bf16* __restrict__ w3h, __bf16* __restrict__ w3l)
{
    int gid = blockIdx.x * 256 + threadIdx.x;
    const float* src;
    __bf16 *oh, *ol;
    int e, N;
    if (gid < 65536)       { src = W1; oh = w1h; ol = w1l; e = gid;          N = 256; }
    else if (gid < 131072) { src = W2; oh = w2h; ol = w2l; e = gid - 65536;  N = 256; }
    else if (gid < 135168) { src = W3; oh = w3h; ol = w3l; e = gid - 131072; N = 16;  }
    else return;

    int j  = e & 7;
    int n  = (e >> 3) & (N - 1);
    int kg = e >> 3; kg = (N == 256) ? (kg >> 8) : (kg >> 4);
    int k  = kg * 8 + j;
    float v = src[k * N + n];
    __bf16 h = (__bf16)v;
    oh[e] = h;
    ol[e] = (__bf16)(v - (float)h);
}

// ---------------------------------------------------------------------------
// Kernel 1: 32-row tile, split-bf16 3-pass MFMA. NO launch-bounds register
// cap (R5's (256,4) forced a 64-VGPR cap -> 54MB scratch spill). Full kc
// unroll so the compiler pipelines B loads across iterations.
// ---------------------------------------------------------------------------
__global__ __launch_bounds__(256) void mlp_softk_mfma(
    const float* __restrict__ X, const int* __restrict__ mask,
    const __bf16* __restrict__ W1h, const __bf16* __restrict__ W1l,
    const float* __restrict__ b1,
    const __bf16* __restrict__ W2h, const __bf16* __restrict__ W2l,
    const float* __restrict__ b2,
    const __bf16* __restrict__ W3h, const __bf16* __restrict__ W3l,
    float* __restrict__ P)
{
    __shared__ __bf16 Ahi[TM * HDIM];   // 16 KB
    __shared__ __bf16 Alo[TM * HDIM];   // 16 KB

    const int tid  = threadIdx.x;
    const int lane = tid & 63;
    const int w    = tid >> 6;      // wave id: owns cols 64w..64w+63
    const int l15  = lane & 15;
    const int quad = lane >> 4;
    const long r0  = (long)blockIdx.x * TM;

    // ---- stage X tile -> LDS as split bf16 (swizzled) ----
    {
        const float4* Xt = (const float4*)(X + r0 * HDIM);
        #pragma unroll
        for (int t = 0; t < (TM * HDIM / 4) / 256; ++t) {
            int v4  = tid + t * 256;
            float4 f = Xt[v4];
            int row = v4 >> 6;            // 64 float4 per row
            int col = (v4 & 63) << 2;
            int kgs = (col >> 3) ^ (row & 31);
            int base = row * HDIM + kgs * 8 + (col & 7);
            __bf16 h0 = (__bf16)f.x, h1 = (__bf16)f.y,
                   h2 = (__bf16)f.z, h3 = (__bf16)f.w;
            bf16x4 hv = {h0, h1, h2, h3};
            bf16x4 lv = {(__bf16)(f.x - (float)h0), (__bf16)(f.y - (float)h1),
                         (__bf16)(f.z - (float)h2), (__bf16)(f.w - (float)h3)};
            *(bf16x4*)(&Ahi[base]) = hv;
            *(bf16x4*)(&Alo[base]) = lv;
        }
    }
    __syncthreads();

    f32x4 acc[2][4];

    auto layer = [&](const __bf16* __restrict__ Wh, const __bf16* __restrict__ Wl,
                     const float* __restrict__ bias) {
        #pragma unroll
        for (int mt = 0; mt < 2; ++mt)
            #pragma unroll
            for (int nt = 0; nt < 4; ++nt)
                acc[mt][nt] = (f32x4){0.f, 0.f, 0.f, 0.f};

        #pragma unroll
        for (int kc = 0; kc < 8; ++kc) {
            bf16x8 bh[4], bl[4], ah[2], al[2];
            #pragma unroll
            for (int nt = 0; nt < 4; ++nt) {
                int n  = w * 64 + nt * 16 + l15;
                int kg = kc * 4 + quad;
                bh[nt] = *(const bf16x8*)(Wh + (kg * HDIM + n) * 8);
                bl[nt] = *(const bf16x8*)(Wl + (kg * HDIM + n) * 8);
            }
            #pragma unroll
            for (int mt = 0; mt < 2; ++mt) {
                int row = mt * 16 + l15;
                int kgs = (kc * 4 + quad) ^ (row & 31);
                ah[mt] = *(const bf16x8*)(&Ahi[row * HDIM + kgs * 8]);
                al[mt] = *(const bf16x8*)(&Alo[row * HDIM + kgs * 8]);
            }
            #pragma unroll
            for (int mt = 0; mt < 2; ++mt)
                #pragma unroll
                for (int nt = 0; nt < 4; ++nt) {
                    acc[mt][nt] = __builtin_amdgcn_mfma_f32_16x16x32_bf16(
                        ah[mt], bh[nt], acc[mt][nt], 0, 0, 0);
                    acc[mt][nt] = __builtin_amdgcn_mfma_f32_16x16x32_bf16(
                        al[mt], bh[nt], acc[mt][nt], 0, 0, 0);
                    acc[mt][nt] = __builtin_amdgcn_mfma_f32_16x16x32_bf16(
                        ah[mt], bl[nt], acc[mt][nt], 0, 0, 0);
                }
        }
        __syncthreads();   // everyone done reading A before overwrite

        float bias_v[4];
        #pragma unroll
        for (int nt = 0; nt < 4; ++nt) bias_v[nt] = bias[w * 64 + nt * 16 + l15];
        #pragma unroll
        for (int mt = 0; mt < 2; ++mt)
            #pragma unroll
            for (int nt = 0; nt < 4; ++nt)
                #pragma unroll
                for (int r = 0; r < 4; ++r) {
                    float v = fmaxf(acc[mt][nt][r] + bias_v[nt], 0.f);
                    int row = mt * 16 + quad * 4 + r;   // C layout: row=(l>>4)*4+reg
                    int col = w * 64 + nt * 16 + l15;   //           col=l&15
                    int idx = row * HDIM + (((col >> 3) ^ (row & 31)) * 8) + (col & 7);
                    __bf16 h = (__bf16)v;
                    Ahi[idx] = h;
                    Alo[idx] = (__bf16)(v - (float)h);
                }
        __syncthreads();
    };

    layer(W1h, W1l, b1);
    layer(W2h, W2l, b2);

    // ---- logits: waves 0,1 each handle one 16-row m-tile (TM=32) ----
    if (w < 2) {
        f32x4 lg = {0.f, 0.f, 0.f, 0.f};
        #pragma unroll
        for (int kc = 0; kc < 8; ++kc) {
            int row = w * 16 + l15;
            int kg  = kc * 4 + quad;
            int kgs = kg ^ (row & 31);
            bf16x8 ah = *(const bf16x8*)(&Ahi[row * HDIM + kgs * 8]);
            bf16x8 al = *(const bf16x8*)(&Alo[row * HDIM + kgs * 8]);
            bf16x8 bh = *(const bf16x8*)(W3h + (kg * KDIM + l15) * 8);
            bf16x8 bl = *(const bf16x8*)(W3l + (kg * KDIM + l15) * 8);
            lg = __builtin_amdgcn_mfma_f32_16x16x32_bf16(ah, bh, lg, 0, 0, 0);
            lg = __builtin_amdgcn_mfma_f32_16x16x32_bf16(al, bh, lg, 0, 0, 0);
            lg = __builtin_amdgcn_mfma_f32_16x16x32_bf16(ah, bl, lg, 0, 0, 0);
        }

        // softmax over k: 16 lanes of a quad-group hold the 16 cols of a row
        #pragma unroll
        for (int r = 0; r < 4; ++r) {
            float v  = lg[r];
            float mx = v;
            mx = fmaxf(mx, __shfl_xor(mx, 1));
            mx = fmaxf(mx, __shfl_xor(mx, 2));
            mx = fmaxf(mx, __shfl_xor(mx, 4));
            mx = fmaxf(mx, __shfl_xor(mx, 8));
            float e = __expf(v - mx);
            float s = e;
            s += __shfl_xor(s, 1);
            s += __shfl_xor(s, 2);
            s += __shfl_xor(s, 4);
            s += __shfl_xor(s, 8);
            int grow = (int)r0 + w * 16 + quad * 4 + r;
            int mv   = mask[grow];
            float ov = mv ? (e / s) * 0.25f : -2500.0f;   // (-10000)/sqrt(16)
            P[(long)grow * KDIM + l15] = ov;
        }
    }
}

// ---------------------------------------------------------------------------
// Kernel 2: per-b. Phase 1: softmax over S of P[b] (exp(-2500)==0 handles
// the mask) * time_f_w -> wl in LDS. Phase 2: wave (sh,hh) covers s-half sh,
// h-half hh: lane owns 2 h-cols, X read exactly once, each 4 ds_read_b128
// feeds 64 FMAs. Cross-wave s-reduce via LDS.
// ---------------------------------------------------------------------------
__global__ __launch_bounds__(256) void softs_agg_kernel(
    const float* __restrict__ X, const float* __restrict__ tf,
    const float* __restrict__ P, float* __restrict__ out)
{
    __shared__ float wl[SDIM * KDIM];
    __shared__ float tfl[SDIM];
    __shared__ float psum[256];
    __shared__ float invk[KDIM];
    __shared__ float red[KDIM * HDIM];

    const int tid = threadIdx.x;
    const int b   = blockIdx.x;

    const float* Pb = P + (long)b * SDIM * KDIM;
    float ps = 0.f;
    #pragma unroll
    for (int t = 0; t < 13; ++t) {
        int i = tid + t * 256;
        if (i < SDIM * KDIM) {
            float e = __expf(Pb[i]);
            wl[i] = e;
            ps += e;
        }
    }
    psum[tid] = ps;
    if (tid < SDIM) tfl[tid] = tf[b * SDIM + tid];
    __syncthreads();

    if (tid < KDIM) {
        float s = 0.f;
        #pragma unroll
        for (int g = 0; g < 16; ++g) s += psum[tid + g * 16];
        invk[tid] = 1.f / s;
    }
    __syncthreads();

    #pragma unroll
    for (int t = 0; t < 13; ++t) {
        int i = tid + t * 256;
        if (i < SDIM * KDIM) wl[i] *= tfl[i >> 4] * invk[i & 15];
    }
    __syncthreads();

    const int wv = tid >> 6;
    const int sh = wv >> 1;      // s-half: [100*sh, 100*sh+100)
    const int hh = wv & 1;       // h-half: cols 128*hh..128*hh+127
    const int ln = tid & 63;     // lane -> 2 h-cols

    float accx[KDIM], accy[KDIM];
    #pragma unroll
    for (int k = 0; k < KDIM; ++k) { accx[k] = 0.f; accy[k] = 0.f; }

    const float2* Xb  = (const float2*)(X + (long)b * SDIM * HDIM) + hh * 64 + ln;
    const f32x4*  wl4 = (const f32x4*)wl;
    const int s0 = sh * 100;
    #pragma unroll 4
    for (int si = 0; si < 100; ++si) {
        int s = s0 + si;
        float2 x = Xb[(long)s * (HDIM / 2)];
        f32x4 d0 = wl4[s * 4 + 0];
        f32x4 d1 = wl4[s * 4 + 1];
        f32x4 d2 = wl4[s * 4 + 2];
        f32x4 d3 = wl4[s * 4 + 3];
        #pragma unroll
        for (int j = 0; j < 4; ++j) {
            accx[0 + j]  = fmaf(x.x, d0[j], accx[0 + j]);
            accx[4 + j]  = fmaf(x.x, d1[j], accx[4 + j]);
            accx[8 + j]  = fmaf(x.x, d2[j], accx[8 + j]);
            accx[12 + j] = fmaf(x.x, d3[j], accx[12 + j]);
            accy[0 + j]  = fmaf(x.y, d0[j], accy[0 + j]);
            accy[4 + j]  = fmaf(x.y, d1[j], accy[4 + j]);
            accy[8 + j]  = fmaf(x.y, d2[j], accy[8 + j]);
            accy[12 + j] = fmaf(x.y, d3[j], accy[12 + j]);
        }
    }

    if (sh == 1) {
        #pragma unroll
        for (int k = 0; k < KDIM; ++k) {
            red[k * HDIM + hh * 128 + 2 * ln + 0] = accx[k];
            red[k * HDIM + hh * 128 + 2 * ln + 1] = accy[k];
        }
    }
    __syncthreads();
    if (sh == 0) {
        float* ob = out + (long)b * KDIM * HDIM + hh * 128 + 2 * ln;
        #pragma unroll
        for (int k = 0; k < KDIM; ++k) {
            float2 o;
            o.x = accx[k] + red[k * HDIM + hh * 128 + 2 * ln + 0];
            o.y = accy[k] + red[k * HDIM + hh * 128 + 2 * ln + 1];
            *(float2*)(ob + (long)k * HDIM) = o;
        }
    }
}

extern "C" void kernel_launch(void* const* d_in, const int* in_sizes, int n_in,
                              void* d_out, int out_size, void* d_ws, size_t ws_size,
                              hipStream_t stream) {
    (void)in_sizes; (void)n_in; (void)out_size; (void)ws_size;
    const float* X    = (const float*)d_in[0];
    const int*   mask = (const int*)  d_in[1];
    const float* tf   = (const float*)d_in[2];
    const float* W1   = (const float*)d_in[3];
    const float* b1   = (const float*)d_in[4];
    const float* W2   = (const float*)d_in[5];
    const float* b2   = (const float*)d_in[6];
    const float* W3   = (const float*)d_in[7];
    float* out = (float*)d_out;

    char* ws = (char*)d_ws;
    float*  P   = (float*)ws;                          // 102400*16*4 = 6,553,600 B
    __bf16* w1h = (__bf16*)(ws + 6553600);             // 65536 elems each
    __bf16* w1l = w1h + 65536;
    __bf16* w2h = w1l + 65536;
    __bf16* w2l = w2h + 65536;
    __bf16* w3h = w2l + 65536;                         // 4096 elems each
    __bf16* w3l = w3h + 4096;

    pack_all<<<528, 256, 0, stream>>>(W1, W2, W3, w1h, w1l, w2h, w2l, w3h, w3l);
    mlp_softk_mfma<<<NROWS / TM, 256, 0, stream>>>(X, mask, w1h, w1l, b1,
                                                   w2h, w2l, b2, w3h, w3l, P);
    softs_agg_kernel<<<BDIM, 256, 0, stream>>>(X, tf, P, out);
}

// Round 8
// 260.530 us; speedup vs baseline: 1.2494x; 1.0117x over previous
//
#include <hip/hip_runtime.h>
#include <math.h>

#define HDIM 256
#define KDIM 16
#define SDIM 200
#define BDIM 512
#define NROWS (BDIM * SDIM)   // 102400
#define TM 32                 // rows per block in kernel 1 (32KB LDS)

typedef __bf16 bf16x8 __attribute__((ext_vector_type(8)));
typedef __bf16 bf16x4 __attribute__((ext_vector_type(4)));
typedef float  f32x4  __attribute__((ext_vector_type(4)));

// ---------------------------------------------------------------------------
// Fused pack: W1, W2, W3 -> fragment-ready split-bf16 layout
//   dst[((k>>3)*N + n)*8 + (k&7)] = hi/lo bf16 of W[k*N + n]
// ---------------------------------------------------------------------------
__global__ __launch_bounds__(256) void pack_all(
    const float* __restrict__ W1, const float* __restrict__ W2,
    const float* __restrict__ W3,
    __bf16* __restrict__ w1h, __bf16* __restrict__ w1l,
    __bf16* __restrict__ w2h, __bf16* __restrict__ w2l,
    __bf16* __restrict__ w3h, __bf16* __restrict__ w3l)
{
    int gid = blockIdx.x * 256 + threadIdx.x;
    const float* src;
    __bf16 *oh, *ol;
    int e, N;
    if (gid < 65536)       { src = W1; oh = w1h; ol = w1l; e = gid;          N = 256; }
    else if (gid < 131072) { src = W2; oh = w2h; ol = w2l; e = gid - 65536;  N = 256; }
    else if (gid < 135168) { src = W3; oh = w3h; ol = w3l; e = gid - 131072; N = 16;  }
    else return;

    int j  = e & 7;
    int n  = (e >> 3) & (N - 1);
    int kg = e >> 3; kg = (N == 256) ? (kg >> 8) : (kg >> 4);
    int k  = kg * 8 + j;
    float v = src[k * N + n];
    __bf16 h = (__bf16)v;
    oh[e] = h;
    ol[e] = (__bf16)(v - (float)h);
}

// ---------------------------------------------------------------------------
// Kernel 1 (UNCHANGED from round 7: 125.5us measured): 32-row tile,
// split-bf16 3-pass MFMA, no launch-bounds register cap.
// ---------------------------------------------------------------------------
__global__ __launch_bounds__(256) void mlp_softk_mfma(
    const float* __restrict__ X, const int* __restrict__ mask,
    const __bf16* __restrict__ W1h, const __bf16* __restrict__ W1l,
    const float* __restrict__ b1,
    const __bf16* __restrict__ W2h, const __bf16* __restrict__ W2l,
    const float* __restrict__ b2,
    const __bf16* __restrict__ W3h, const __bf16* __restrict__ W3l,
    float* __restrict__ P)
{
    __shared__ __bf16 Ahi[TM * HDIM];   // 16 KB
    __shared__ __bf16 Alo[TM * HDIM];   // 16 KB

    const int tid  = threadIdx.x;
    const int lane = tid & 63;
    const int w    = tid >> 6;      // wave id: owns cols 64w..64w+63
    const int l15  = lane & 15;
    const int quad = lane >> 4;
    const long r0  = (long)blockIdx.x * TM;

    // ---- stage X tile -> LDS as split bf16 (swizzled) ----
    {
        const float4* Xt = (const float4*)(X + r0 * HDIM);
        #pragma unroll
        for (int t = 0; t < (TM * HDIM / 4) / 256; ++t) {
            int v4  = tid + t * 256;
            float4 f = Xt[v4];
            int row = v4 >> 6;            // 64 float4 per row
            int col = (v4 & 63) << 2;
            int kgs = (col >> 3) ^ (row & 31);
            int base = row * HDIM + kgs * 8 + (col & 7);
            __bf16 h0 = (__bf16)f.x, h1 = (__bf16)f.y,
                   h2 = (__bf16)f.z, h3 = (__bf16)f.w;
            bf16x4 hv = {h0, h1, h2, h3};
            bf16x4 lv = {(__bf16)(f.x - (float)h0), (__bf16)(f.y - (float)h1),
                         (__bf16)(f.z - (float)h2), (__bf16)(f.w - (float)h3)};
            *(bf16x4*)(&Ahi[base]) = hv;
            *(bf16x4*)(&Alo[base]) = lv;
        }
    }
    __syncthreads();

    f32x4 acc[2][4];

    auto layer = [&](const __bf16* __restrict__ Wh, const __bf16* __restrict__ Wl,
                     const float* __restrict__ bias) {
        #pragma unroll
        for (int mt = 0; mt < 2; ++mt)
            #pragma unroll
            for (int nt = 0; nt < 4; ++nt)
                acc[mt][nt] = (f32x4){0.f, 0.f, 0.f, 0.f};

        #pragma unroll
        for (int kc = 0; kc < 8; ++kc) {
            bf16x8 bh[4], bl[4], ah[2], al[2];
            #pragma unroll
            for (int nt = 0; nt < 4; ++nt) {
                int n  = w * 64 + nt * 16 + l15;
                int kg = kc * 4 + quad;
                bh[nt] = *(const bf16x8*)(Wh + (kg * HDIM + n) * 8);
                bl[nt] = *(const bf16x8*)(Wl + (kg * HDIM + n) * 8);
            }
            #pragma unroll
            for (int mt = 0; mt < 2; ++mt) {
                int row = mt * 16 + l15;
                int kgs = (kc * 4 + quad) ^ (row & 31);
                ah[mt] = *(const bf16x8*)(&Ahi[row * HDIM + kgs * 8]);
                al[mt] = *(const bf16x8*)(&Alo[row * HDIM + kgs * 8]);
            }
            #pragma unroll
            for (int mt = 0; mt < 2; ++mt)
                #pragma unroll
                for (int nt = 0; nt < 4; ++nt) {
                    acc[mt][nt] = __builtin_amdgcn_mfma_f32_16x16x32_bf16(
                        ah[mt], bh[nt], acc[mt][nt], 0, 0, 0);
                    acc[mt][nt] = __builtin_amdgcn_mfma_f32_16x16x32_bf16(
                        al[mt], bh[nt], acc[mt][nt], 0, 0, 0);
                    acc[mt][nt] = __builtin_amdgcn_mfma_f32_16x16x32_bf16(
                        ah[mt], bl[nt], acc[mt][nt], 0, 0, 0);
                }
        }
        __syncthreads();   // everyone done reading A before overwrite

        float bias_v[4];
        #pragma unroll
        for (int nt = 0; nt < 4; ++nt) bias_v[nt] = bias[w * 64 + nt * 16 + l15];
        #pragma unroll
        for (int mt = 0; mt < 2; ++mt)
            #pragma unroll
            for (int nt = 0; nt < 4; ++nt)
                #pragma unroll
                for (int r = 0; r < 4; ++r) {
                    float v = fmaxf(acc[mt][nt][r] + bias_v[nt], 0.f);
                    int row = mt * 16 + quad * 4 + r;   // C layout: row=(l>>4)*4+reg
                    int col = w * 64 + nt * 16 + l15;   //           col=l&15
                    int idx = row * HDIM + (((col >> 3) ^ (row & 31)) * 8) + (col & 7);
                    __bf16 h = (__bf16)v;
                    Ahi[idx] = h;
                    Alo[idx] = (__bf16)(v - (float)h);
                }
        __syncthreads();
    };

    layer(W1h, W1l, b1);
    layer(W2h, W2l, b2);

    // ---- logits: waves 0,1 each handle one 16-row m-tile (TM=32) ----
    if (w < 2) {
        f32x4 lg = {0.f, 0.f, 0.f, 0.f};
        #pragma unroll
        for (int kc = 0; kc < 8; ++kc) {
            int row = w * 16 + l15;
            int kg  = kc * 4 + quad;
            int kgs = kg ^ (row & 31);
            bf16x8 ah = *(const bf16x8*)(&Ahi[row * HDIM + kgs * 8]);
            bf16x8 al = *(const bf16x8*)(&Alo[row * HDIM + kgs * 8]);
            bf16x8 bh = *(const bf16x8*)(W3h + (kg * KDIM + l15) * 8);
            bf16x8 bl = *(const bf16x8*)(W3l + (kg * KDIM + l15) * 8);
            lg = __builtin_amdgcn_mfma_f32_16x16x32_bf16(ah, bh, lg, 0, 0, 0);
            lg = __builtin_amdgcn_mfma_f32_16x16x32_bf16(al, bh, lg, 0, 0, 0);
            lg = __builtin_amdgcn_mfma_f32_16x16x32_bf16(ah, bl, lg, 0, 0, 0);
        }

        // softmax over k: 16 lanes of a quad-group hold the 16 cols of a row
        #pragma unroll
        for (int r = 0; r < 4; ++r) {
            float v  = lg[r];
            float mx = v;
            mx = fmaxf(mx, __shfl_xor(mx, 1));
            mx = fmaxf(mx, __shfl_xor(mx, 2));
            mx = fmaxf(mx, __shfl_xor(mx, 4));
            mx = fmaxf(mx, __shfl_xor(mx, 8));
            float e = __expf(v - mx);
            float s = e;
            s += __shfl_xor(s, 1);
            s += __shfl_xor(s, 2);
            s += __shfl_xor(s, 4);
            s += __shfl_xor(s, 8);
            int grow = (int)r0 + w * 16 + quad * 4 + r;
            int mv   = mask[grow];
            float ov = mv ? (e / s) * 0.25f : -2500.0f;   // (-10000)/sqrt(16)
            P[(long)grow * KDIM + l15] = ov;
        }
    }
}

// ---------------------------------------------------------------------------
// Kernel 2 REWRITE: 512 threads = 8 waves = (s-quarter sq, k-half kh).
// Lane owns a float4 of h (one wave covers all 256 h-cols -> 1KB coalesced
// X loads, 5 in flight via unroll). acc = 8 k x f32x4 = 32 VGPRs.
// Single-barrier LDS tree reduce over the 4 s-quarters.
// psum is aliased onto red (phases barrier-separated) to stay < 64KB LDS.
// ---------------------------------------------------------------------------
__global__ __launch_bounds__(512) void softs_agg_kernel(
    const float* __restrict__ X, const float* __restrict__ tf,
    const float* __restrict__ P, float* __restrict__ out)
{
    __shared__ float wl[SDIM * KDIM];          // 12.8 KB
    __shared__ float tfl[SDIM];                // 0.8 KB
    __shared__ float invk[KDIM];
    __shared__ float red[6 * 8 * HDIM];        // 48 KB: slot (sq-1)*2+kh
    float* psum = red;                         // alias (dead before red use)

    const int tid = threadIdx.x;
    const int b   = blockIdx.x;

    // ---- phase 1: column softmax over S (exp(-2500)==0 handles the mask) ----
    const float* Pb = P + (long)b * SDIM * KDIM;
    float ps = 0.f;
    #pragma unroll
    for (int t = 0; t < 7; ++t) {
        int i = tid + t * 512;
        if (i < SDIM * KDIM) {
            float e = __expf(Pb[i]);
            wl[i] = e;
            ps += e;
        }
    }
    psum[tid] = ps;
    if (tid < SDIM) tfl[tid] = tf[b * SDIM + tid];
    __syncthreads();

    if (tid < KDIM) {
        float s = 0.f;
        #pragma unroll
        for (int g = 0; g < 32; ++g) s += psum[tid + g * 16];   // 512%16==0
        invk[tid] = 1.f / s;
    }
    __syncthreads();

    #pragma unroll
    for (int t = 0; t < 7; ++t) {
        int i = tid + t * 512;
        if (i < SDIM * KDIM) wl[i] *= tfl[i >> 4] * invk[i & 15];
    }
    __syncthreads();

    // ---- phase 2: out[b,k,h] = sum_s X[b,s,h] * wl[s,k] ----
    const int wv = tid >> 6;
    const int sq = wv >> 1;      // s-quarter: [50*sq, 50*sq+50)
    const int kh = wv & 1;       // k-half: k in [8*kh, 8*kh+8)
    const int ln = tid & 63;     // lane -> h-cols 4*ln..4*ln+3

    f32x4 acc[8];
    #pragma unroll
    for (int j = 0; j < 8; ++j) acc[j] = (f32x4){0.f, 0.f, 0.f, 0.f};

    const f32x4* Xb4 = (const f32x4*)(X + (long)b * SDIM * HDIM);
    const f32x4* wl4 = (const f32x4*)wl;
    const int s0 = sq * 50;
    #pragma unroll 5
    for (int si = 0; si < 50; ++si) {
        int s = s0 + si;
        f32x4 x  = Xb4[s * 64 + ln];             // 1KB coalesced per wave
        f32x4 d0 = wl4[s * 4 + 2 * kh + 0];      // wave-uniform LDS b128
        f32x4 d1 = wl4[s * 4 + 2 * kh + 1];
        #pragma unroll
        for (int j = 0; j < 4; ++j) {
            acc[j]     += x * d0[j];             // k = 8kh + j
            acc[4 + j] += x * d1[j];             // k = 8kh + 4 + j
        }
    }

    // ---- tree reduce over s-quarters: sq>0 deposit, sq==0 sums + stores ----
    if (sq > 0) {
        float* rp = red + (((sq - 1) * 2 + kh) * 8) * HDIM;
        #pragma unroll
        for (int j = 0; j < 8; ++j)
            *(f32x4*)(rp + j * HDIM + 4 * ln) = acc[j];
    }
    __syncthreads();
    if (sq == 0) {
        #pragma unroll
        for (int p = 0; p < 3; ++p) {
            const float* rp = red + ((p * 2 + kh) * 8) * HDIM;
            #pragma unroll
            for (int j = 0; j < 8; ++j)
                acc[j] += *(const f32x4*)(rp + j * HDIM + 4 * ln);
        }
        float* ob = out + (long)b * KDIM * HDIM + kh * 8 * HDIM;
        #pragma unroll
        for (int j = 0; j < 8; ++j)
            *(f32x4*)(ob + j * HDIM + 4 * ln) = acc[j];
    }
}

extern "C" void kernel_launch(void* const* d_in, const int* in_sizes, int n_in,
                              void* d_out, int out_size, void* d_ws, size_t ws_size,
                              hipStream_t stream) {
    (void)in_sizes; (void)n_in; (void)out_size; (void)ws_size;
    const float* X    = (const float*)d_in[0];
    const int*   mask = (const int*)  d_in[1];
    const float* tf   = (const float*)d_in[2];
    const float* W1   = (const float*)d_in[3];
    const float* b1   = (const float*)d_in[4];
    const float* W2   = (const float*)d_in[5];
    const float* b2   = (const float*)d_in[6];
    const float* W3   = (const float*)d_in[7];
    float* out = (float*)d_out;

    char* ws = (char*)d_ws;
    float*  P   = (float*)ws;                          // 102400*16*4 = 6,553,600 B
    __bf16* w1h = (__bf16*)(ws + 6553600);             // 65536 elems each
    __bf16* w1l = w1h + 65536;
    __bf16* w2h = w1l + 65536;
    __bf16* w2l = w2h + 65536;
    __bf16* w3h = w2l + 65536;                         // 4096 elems each
    __bf16* w3l = w3h + 4096;

    pack_all<<<528, 256, 0, stream>>>(W1, W2, W3, w1h, w1l, w2h, w2l, w3h, w3l);
    mlp_softk_mfma<<<NROWS / TM, 256, 0, stream>>>(X, mask, w1h, w1l, b1,
                                                   w2h, w2l, b2, w3h, w3l, P);
    softs_agg_kernel<<<BDIM, 512, 0, stream>>>(X, tf, P, out);
}